// Round 1
// baseline (8818.945 us; speedup 1.0000x reference)
//
#include <hip/hip_runtime.h>
#include <cmath>

// Problem constants (from reference)
namespace {
constexpr int Bc = 256, Tc = 64, Lc = 16, Ec = 64, Hc = 256, Rc = 512, LEc = 64, NLc = 17;
constexpr int Nc = Bc * Tc;     // 16384 segments
constexpr int G4 = 4 * Hc;      // 1024 LSTM gate cols
constexpr int KX = Rc + LEc;    // 576 GRU input dim

__device__ __forceinline__ float sigm(float x) { return 1.f / (1.f + expf(-x)); }

// ---------------------------------------------------------------------------
// proj[dir][tok][g] = Wih[g,:] . seg_emb[tok,:] + bih[g] + bhh[g]
// (tokens only take 3 values -> the whole input projection is a 3-row LUT)
// ---------------------------------------------------------------------------
__global__ __launch_bounds__(256) void proj_kernel(
    const float* __restrict__ Wih_f, const float* __restrict__ bih_f, const float* __restrict__ bhh_f,
    const float* __restrict__ Wih_b, const float* __restrict__ bih_b, const float* __restrict__ bhh_b,
    const float* __restrict__ seg_emb,
    float* __restrict__ proj_f, float* __restrict__ proj_b)
{
    int o = blockIdx.x * blockDim.x + threadIdx.x;
    if (o >= 2 * 3 * G4) return;
    int dir = o / (3 * G4);
    int rem = o - dir * 3 * G4;
    int tk  = rem / G4;
    int g   = rem - tk * G4;
    const float* Wih = dir ? Wih_b : Wih_f;
    const float* bih = dir ? bih_b : bih_f;
    const float* bhh = dir ? bhh_b : bhh_f;
    float s = bih[g] + bhh[g];
    const float* w = Wih + (size_t)g * Ec;
    const float* e = seg_emb + (size_t)tk * Ec;
    #pragma unroll 16
    for (int k = 0; k < Ec; ++k) s += w[k] * e[k];
    (dir ? proj_b : proj_f)[tk * G4 + g] = s;
}

// ---------------------------------------------------------------------------
// One LSTM time step, both directions (blockIdx.z), fused gate GEMM + cell.
// gates[n][q*256+j] = sum_k h_in[n][k] * Whh[q*256+j][k]  (+ proj LUT in epilogue)
// Block tile: 64 rows x 32 h-cols x 4 gates. Thread: 8 rows x 1 col x 4 gates.
// h ping-pong (cross-block read/write hazard), c in-place (thread-exclusive).
// Masked rows (pos >= len): h_out = h_in, c untouched.
// ---------------------------------------------------------------------------
__global__ __launch_bounds__(256) void lstm_step_kernel(
    const float* __restrict__ Whh_f, const float* __restrict__ Whh_b,
    const float* __restrict__ proj_f, const float* __restrict__ proj_b,
    const int* __restrict__ tokens, const int* __restrict__ seg_lens,
    const float* __restrict__ h_in_f, float* __restrict__ h_out_f,
    const float* __restrict__ h_in_b, float* __restrict__ h_out_b,
    float* __restrict__ c_f, float* __restrict__ c_b,
    int step)
{
    const int dir = blockIdx.z;
    const float* Whh  = dir ? Whh_b  : Whh_f;
    const float* proj = dir ? proj_b : proj_f;
    const float* h_in = dir ? h_in_b : h_in_f;
    float* h_out      = dir ? h_out_b : h_out_f;
    float* c          = dir ? c_b    : c_f;
    const int pos = dir ? (Lc - 1 - step) : step;   // original position processed

    const int n0 = blockIdx.x * 64;
    const int j0 = blockIdx.y * 32;

    __shared__ float Hs[64][64];     // [row][k]   (k-contig, 16B aligned)
    __shared__ float Ws[128][68];    // [q*32+jj][k], pad 68 -> 16B-aligned, 4-way max

    const int tid = threadIdx.x;
    const int jj = tid & 31;
    const int rr = tid >> 5;

    float acc[8][4];
    #pragma unroll
    for (int m = 0; m < 8; ++m)
        #pragma unroll
        for (int q = 0; q < 4; ++q) acc[m][q] = 0.f;

    for (int k0 = 0; k0 < Hc; k0 += 64) {
        // stage H tile: 64 rows x 64 k  (1024 float4, 4/thread, coalesced)
        #pragma unroll
        for (int i = 0; i < 4; ++i) {
            int t4 = tid + i * 256;
            int row = t4 >> 4, k4 = t4 & 15;
            *(float4*)&Hs[row][k4 * 4] =
                *(const float4*)&h_in[(size_t)(n0 + row) * Hc + k0 + k4 * 4];
        }
        // stage W tile: 128 gate-rows x 64 k (2048 float4, 8/thread)
        #pragma unroll
        for (int i = 0; i < 8; ++i) {
            int t4 = tid + i * 256;
            int grow = t4 >> 4, k4 = t4 & 15;
            int q = grow >> 5, jw = grow & 31;
            *(float4*)&Ws[grow][k4 * 4] =
                *(const float4*)&Whh[(size_t)(q * Hc + j0 + jw) * Hc + k0 + k4 * 4];
        }
        __syncthreads();
        #pragma unroll 4
        for (int k4 = 0; k4 < 16; ++k4) {
            float4 wv[4];
            #pragma unroll
            for (int q = 0; q < 4; ++q) wv[q] = *(const float4*)&Ws[q * 32 + jj][k4 * 4];
            #pragma unroll
            for (int m = 0; m < 8; ++m) {
                float4 a = *(const float4*)&Hs[rr + 8 * m][k4 * 4];
                #pragma unroll
                for (int q = 0; q < 4; ++q)
                    acc[m][q] += a.x * wv[q].x + a.y * wv[q].y + a.z * wv[q].z + a.w * wv[q].w;
            }
        }
        __syncthreads();
    }

    const int j = j0 + jj;
    #pragma unroll
    for (int m = 0; m < 8; ++m) {
        int n = n0 + rr + 8 * m;
        size_t idx = (size_t)n * Hc + j;
        int len = seg_lens[n];
        if (pos < len) {
            int tok = tokens[n * Lc + pos];
            const float* pr = proj + (size_t)tok * G4;
            float gi = acc[m][0] + pr[j];
            float gf = acc[m][1] + pr[Hc + j];
            float gg = acc[m][2] + pr[2 * Hc + j];
            float go = acc[m][3] + pr[3 * Hc + j];
            float cold = c[idx];
            float cn = sigm(gf) * cold + sigm(gi) * tanhf(gg);
            float hn = sigm(go) * tanhf(cn);
            c[idx] = cn;
            h_out[idx] = hn;
        } else {
            h_out[idx] = h_in[idx];   // frozen step: carry state forward
        }
    }
}

// ---------------------------------------------------------------------------
// One GRU decoder step. Fused: gates_h = h_prev @ gWhh^T  (K=512)
//                              gates_i = [hf|hb|lab_emb[prev]] @ gWih^T (K=576)
// Block: 16 rows x 32 h-cols x 3 gate groups. Thread: 2 rows x 1 col.
// n-gate needs gi_n and gh_n separately (r * gh_n), so 4 accumulator groups.
// ---------------------------------------------------------------------------
__global__ __launch_bounds__(256) void gru_step_kernel(
    const float* __restrict__ gWih, const float* __restrict__ gWhh,
    const float* __restrict__ gbih, const float* __restrict__ gbhh,
    const float* __restrict__ hf, const float* __restrict__ hb,
    const float* __restrict__ lab_emb, const int* __restrict__ labels,
    const float* __restrict__ h_prev, float* __restrict__ h_out,
    int t)
{
    const int b0 = blockIdx.x * 16;
    const int j0 = blockIdx.y * 32;
    __shared__ float As[16][64];
    __shared__ float Ws[96][68];
    const int tid = threadIdx.x;
    const int jj = tid & 31;
    const int rr = tid >> 5;

    float accr[2]  = {0.f, 0.f};
    float accz[2]  = {0.f, 0.f};
    float accnh[2] = {0.f, 0.f};
    float accni[2] = {0.f, 0.f};

    // ---- phase 1: recurrent part, K = 512 over gWhh ----
    for (int ki = 0; ki < 8; ++ki) {
        const int k0 = ki * 64;
        {
            int row = tid >> 4, k4 = tid & 15;
            *(float4*)&As[row][k4 * 4] =
                *(const float4*)&h_prev[(size_t)(b0 + row) * Rc + k0 + k4 * 4];
        }
        #pragma unroll
        for (int i = 0; i < 6; ++i) {
            int t4 = tid + i * 256;
            int grow = t4 >> 4, k4 = t4 & 15;
            int q = grow >> 5, jw = grow & 31;
            *(float4*)&Ws[grow][k4 * 4] =
                *(const float4*)&gWhh[(size_t)(q * Rc + j0 + jw) * Rc + k0 + k4 * 4];
        }
        __syncthreads();
        #pragma unroll 4
        for (int k4 = 0; k4 < 16; ++k4) {
            float4 wr = *(const float4*)&Ws[jj][k4 * 4];
            float4 wz = *(const float4*)&Ws[32 + jj][k4 * 4];
            float4 wn = *(const float4*)&Ws[64 + jj][k4 * 4];
            #pragma unroll
            for (int m = 0; m < 2; ++m) {
                float4 a = *(const float4*)&As[rr + 8 * m][k4 * 4];
                accr[m]  += a.x * wr.x + a.y * wr.y + a.z * wr.z + a.w * wr.w;
                accz[m]  += a.x * wz.x + a.y * wz.y + a.z * wz.z + a.w * wz.w;
                accnh[m] += a.x * wn.x + a.y * wn.y + a.z * wn.z + a.w * wn.w;
            }
        }
        __syncthreads();
    }

    // ---- phase 2: input part, K = 576 over gWih, x = [hf | hb | lab_emb[prev]] ----
    for (int ki = 0; ki < 9; ++ki) {
        const int k0 = ki * 64;
        {
            int row = tid >> 4, k4 = tid & 15;
            int kp = k0 + k4 * 4;
            int n = (b0 + row) * Tc + t;
            float4 v;
            if (kp < Hc)            v = *(const float4*)&hf[(size_t)n * Hc + kp];
            else if (kp < 2 * Hc)   v = *(const float4*)&hb[(size_t)n * Hc + kp - Hc];
            else {
                int prev = (t == 0) ? NLc : labels[n - 1];
                v = *(const float4*)&lab_emb[(size_t)prev * LEc + kp - 2 * Hc];
            }
            *(float4*)&As[row][k4 * 4] = v;
        }
        #pragma unroll
        for (int i = 0; i < 6; ++i) {
            int t4 = tid + i * 256;
            int grow = t4 >> 4, k4 = t4 & 15;
            int q = grow >> 5, jw = grow & 31;
            *(float4*)&Ws[grow][k4 * 4] =
                *(const float4*)&gWih[(size_t)(q * Rc + j0 + jw) * KX + k0 + k4 * 4];
        }
        __syncthreads();
        #pragma unroll 4
        for (int k4 = 0; k4 < 16; ++k4) {
            float4 wr = *(const float4*)&Ws[jj][k4 * 4];
            float4 wz = *(const float4*)&Ws[32 + jj][k4 * 4];
            float4 wn = *(const float4*)&Ws[64 + jj][k4 * 4];
            #pragma unroll
            for (int m = 0; m < 2; ++m) {
                float4 a = *(const float4*)&As[rr + 8 * m][k4 * 4];
                accr[m]  += a.x * wr.x + a.y * wr.y + a.z * wr.z + a.w * wr.w;
                accz[m]  += a.x * wz.x + a.y * wz.y + a.z * wz.z + a.w * wz.w;
                accni[m] += a.x * wn.x + a.y * wn.y + a.z * wn.z + a.w * wn.w;
            }
        }
        __syncthreads();
    }

    const int j = j0 + jj;
    #pragma unroll
    for (int m = 0; m < 2; ++m) {
        int b = b0 + rr + 8 * m;
        float r  = sigm(accr[m] + gbih[j] + gbhh[j]);
        float z  = sigm(accz[m] + gbih[Rc + j] + gbhh[Rc + j]);
        float ng = tanhf(accni[m] + gbih[2 * Rc + j] + r * (accnh[m] + gbhh[2 * Rc + j]));
        float hold = h_prev[(size_t)b * Rc + j];
        h_out[(size_t)b * Rc + j] = (1.f - z) * ng + z * hold;
    }
}

// ---------------------------------------------------------------------------
// logits[b][t][l] = hs[t][b][:] . Wout[l][:] + bout[l]
// 32-lane group per row; K=512 strided; shfl-xor reduce within 32.
// ---------------------------------------------------------------------------
__global__ __launch_bounds__(256) void logits_kernel(
    const float* __restrict__ hs, const float* __restrict__ Wout,
    const float* __restrict__ bout, float* __restrict__ out)
{
    int tid = threadIdx.x;
    int grp = tid >> 5;
    int lane = tid & 31;
    int n = blockIdx.x * 8 + grp;        // n = b*T + t
    int b = n >> 6;
    int t = n & 63;
    const float* hrow = hs + ((size_t)t * Bc + b) * Rc;
    float hv[16];
    #pragma unroll
    for (int i = 0; i < 16; ++i) hv[i] = hrow[lane + 32 * i];
    for (int l = 0; l < NLc; ++l) {
        const float* w = Wout + (size_t)l * Rc;
        float p = 0.f;
        #pragma unroll
        for (int i = 0; i < 16; ++i) p += hv[i] * w[lane + 32 * i];
        #pragma unroll
        for (int off = 16; off; off >>= 1) p += __shfl_xor(p, off, 32);
        if (lane == 0) out[(size_t)n * NLc + l] = p + bout[l];
    }
}

} // namespace

extern "C" void kernel_launch(void* const* d_in, const int* in_sizes, int n_in,
                              void* d_out, int out_size, void* d_ws, size_t ws_size,
                              hipStream_t stream)
{
    const int*   tokens   = (const int*)d_in[0];
    const int*   seg_lens = (const int*)d_in[1];
    const int*   labels   = (const int*)d_in[2];
    const float* seg_emb  = (const float*)d_in[3];
    const float* Wih_f    = (const float*)d_in[4];
    const float* Whh_f    = (const float*)d_in[5];
    const float* bih_f    = (const float*)d_in[6];
    const float* bhh_f    = (const float*)d_in[7];
    const float* Wih_b    = (const float*)d_in[8];
    const float* Whh_b    = (const float*)d_in[9];
    const float* bih_b    = (const float*)d_in[10];
    const float* bhh_b    = (const float*)d_in[11];
    const float* lab_emb  = (const float*)d_in[12];
    const float* gWih     = (const float*)d_in[13];
    const float* gWhh     = (const float*)d_in[14];
    const float* gbih     = (const float*)d_in[15];
    const float* gbhh     = (const float*)d_in[16];
    const float* Wout     = (const float*)d_in[17];
    const float* bout     = (const float*)d_in[18];
    float* out = (float*)d_out;

    // Workspace layout (floats). Zero region first so one memset covers it.
    //   h_f0, h_b0, c_f, c_b, h0(GRU zero state)  <-- must be zeroed
    //   h_f1, h_b1 (ping-pong, fully written at step 0), proj_f/b, hs
    float* ws = (float*)d_ws;
    const size_t NH = (size_t)Nc * Hc;      // 4,194,304
    float* h_f0   = ws;
    float* h_b0   = h_f0 + NH;
    float* c_f    = h_b0 + NH;
    float* c_b    = c_f + NH;
    float* h0     = c_b + NH;               // [B][R] zeros for GRU t=0
    float* h_f1   = h0 + (size_t)Bc * Rc;
    float* h_b1   = h_f1 + NH;
    float* proj_f = h_b1 + NH;
    float* proj_b = proj_f + 3 * G4;
    float* hs     = proj_b + 3 * G4;        // [T][B][R]
    // total: ~134.8 MB of ws

    size_t zero_bytes = (4 * NH + (size_t)Bc * Rc) * sizeof(float);
    hipMemsetAsync(d_ws, 0, zero_bytes, stream);

    proj_kernel<<<24, 256, 0, stream>>>(Wih_f, bih_f, bhh_f, Wih_b, bih_b, bhh_b,
                                        seg_emb, proj_f, proj_b);

    for (int s = 0; s < Lc; ++s) {
        const float* hinf = (s & 1) ? h_f1 : h_f0;
        float*       houf = (s & 1) ? h_f0 : h_f1;
        const float* hinb = (s & 1) ? h_b1 : h_b0;
        float*       houb = (s & 1) ? h_b0 : h_b1;
        lstm_step_kernel<<<dim3(Nc / 64, Hc / 32, 2), 256, 0, stream>>>(
            Whh_f, Whh_b, proj_f, proj_b, tokens, seg_lens,
            hinf, houf, hinb, houb, c_f, c_b, s);
    }
    // after 16 steps the final hidden states are back in h_f0 / h_b0

    for (int t = 0; t < Tc; ++t) {
        const float* hprev = (t == 0) ? h0 : hs + (size_t)(t - 1) * Bc * Rc;
        gru_step_kernel<<<dim3(Bc / 16, Rc / 32), 256, 0, stream>>>(
            gWih, gWhh, gbih, gbhh, h_f0, h_b0, lab_emb, labels,
            hprev, hs + (size_t)t * Bc * Rc, t);
    }

    logits_kernel<<<Nc / 8, 256, 0, stream>>>(hs, Wout, bout, out);
}

// Round 4
// 2134.006 us; speedup vs baseline: 4.1326x; 4.1326x over previous
//
#include <hip/hip_runtime.h>
#include <cmath>

namespace {
constexpr int NLc = 17;

typedef __attribute__((ext_vector_type(8))) short bf16x8;
typedef __attribute__((ext_vector_type(4))) float f32x4;

__device__ __forceinline__ float sigm(float x) { return 1.f / (1.f + expf(-x)); }

__device__ __forceinline__ unsigned short f2bf(float f) {
    union { float f; unsigned u; } v; v.f = f;
    unsigned r = v.u + 0x7FFF + ((v.u >> 16) & 1);
    return (unsigned short)(r >> 16);
}

// async global->LDS, 16B per lane; lds ptr must be wave-uniform (HW adds lane*16)
__device__ __forceinline__ void async16(void* lds_uniform, const void* gsrc) {
    __builtin_amdgcn_global_load_lds(
        (const __attribute__((address_space(1))) void*)gsrc,
        (__attribute__((address_space(3))) void*)lds_uniform,
        16, 0, 0);
}

// ---------------------------------------------------------------------------
// Prep: Wl[dir][4j+q][k] = bf16(Whh[q*256+j][k]); projP[dir][tok][4j+q] =
//   Wih[q*256+j,:].seg_emb[tok,:] + bih + bhh   (gate order q: i,f,g,o)
// ---------------------------------------------------------------------------
__global__ __launch_bounds__(256) void prep_lstm(
    const float* __restrict__ Whh_f, const float* __restrict__ Whh_b,
    const float* __restrict__ Wih_f, const float* __restrict__ bih_f, const float* __restrict__ bhh_f,
    const float* __restrict__ Wih_b, const float* __restrict__ bih_b, const float* __restrict__ bhh_b,
    const float* __restrict__ seg_emb,
    unsigned short* __restrict__ Wl, float* __restrict__ projP)
{
    int idx = blockIdx.x * 256 + threadIdx.x;   // 0..2047
    int dir = idx >> 10, gpp = idx & 1023;
    int j = gpp >> 2, q = gpp & 3;
    const float* Whh = dir ? Whh_b : Whh_f;
    const float* Wih = dir ? Wih_b : Wih_f;
    const float* bih = dir ? bih_b : bih_f;
    const float* bhh = dir ? bhh_b : bhh_f;
    int src = q * 256 + j;
    const float* wr = Whh + (size_t)src * 256;
    unsigned short* dst = Wl + ((size_t)dir * 1024 + gpp) * 256;
    for (int k = 0; k < 256; ++k) dst[k] = f2bf(wr[k]);
    const float* wi = Wih + (size_t)src * 64;
    float bias = bih[src] + bhh[src];
    for (int tok = 0; tok < 3; ++tok) {
        float s = bias;
        for (int k = 0; k < 64; ++k) s += wi[k] * seg_emb[tok * 64 + k];
        projP[(dir * 3 + tok) * 1024 + gpp] = s;
    }
}

// Wg[4j+q][k]=bf16(gWhh[q*512+j][k]) (q==3 -> 0); gbhhP[4j+q]; Wgi[3j+q][k]; gbihP[3j+q]
__global__ __launch_bounds__(256) void prep_gru(
    const float* __restrict__ gWhh, const float* __restrict__ gbhh,
    const float* __restrict__ gWih, const float* __restrict__ gbih,
    unsigned short* __restrict__ Wg, float* __restrict__ gbhhP,
    unsigned short* __restrict__ Wgi, float* __restrict__ gbihP)
{
    int idx = blockIdx.x * 256 + threadIdx.x;
    if (idx < 2048) {
        int j = idx >> 2, q = idx & 3;
        unsigned short* dst = Wg + (size_t)idx * 512;
        if (q == 3) {
            for (int k = 0; k < 512; ++k) dst[k] = 0;
            gbhhP[idx] = 0.f;
        } else {
            const float* s = gWhh + (size_t)(q * 512 + j) * 512;
            for (int k = 0; k < 512; ++k) dst[k] = f2bf(s[k]);
            gbhhP[idx] = gbhh[q * 512 + j];
        }
    } else if (idx < 2048 + 1536) {
        int i2 = idx - 2048;
        int j = i2 / 3, q = i2 - j * 3;
        const float* s = gWih + (size_t)(q * 512 + j) * 576;
        unsigned short* dst = Wgi + (size_t)i2 * 576;
        for (int k = 0; k < 576; ++k) dst[k] = f2bf(s[k]);
        gbihP[i2] = gbih[q * 512 + j];
    }
}

// ---------------------------------------------------------------------------
// LSTM step: gates^T[g''][n] = sum_k Wl[g''][k] * h_in[n][k]  (MFMA 16x16x32)
// Block 128(g'') x 128(n), 4 waves 2x2, BK=32. Lane's 4 acc regs per frag =
// (i,f,g,o) of one (j,n). c in f32 [dir][j][n] (coalesced). h out bf16 [n][j]
// via per-wave LDS transpose. Masked rows: discard (no copy); parity readout.
// ---------------------------------------------------------------------------
__global__ __launch_bounds__(256) void lstm_step(
    const unsigned short* __restrict__ Wl, const float* __restrict__ projP,
    const int* __restrict__ tokens, const int* __restrict__ seg_lens,
    const unsigned short* __restrict__ hin_f, unsigned short* __restrict__ hout_f,
    const unsigned short* __restrict__ hin_b, unsigned short* __restrict__ hout_b,
    float* __restrict__ cT, int step)
{
    __shared__ __align__(16) char smem[16384];
    const int dir = blockIdx.z;
    const int n0 = blockIdx.x * 128;
    const int g0 = blockIdx.y * 128;
    const unsigned short* W = Wl + (size_t)dir * (1024 * 256);
    const float* proj = projP + dir * 3072;
    const unsigned short* hin = dir ? hin_b : hin_f;
    unsigned short* hout = dir ? hout_b : hout_f;
    float* c = cT + (size_t)dir * (256 * 16384);
    const int pos = dir ? (15 - step) : step;

    const int tid = threadIdx.x;
    const int w = tid >> 6, l = tid & 63;
    const int wm = w & 1, wn = w >> 1;
    const int lrow = l & 15, lkb = (l >> 4) * 16;

    f32x4 acc[4][4];
    #pragma unroll
    for (int mf = 0; mf < 4; ++mf)
        #pragma unroll
        for (int nf = 0; nf < 4; ++nf)
            acc[mf][nf] = (f32x4){0.f, 0.f, 0.f, 0.f};

    for (int it = 0; it < 8; ++it) {
        const int k0 = it * 32;
        #pragma unroll
        for (int rr = 0; rr < 2; ++rr) {
            const int off = (rr * 4 + w) * 1024;
            const int row = (off + l * 16) >> 6;
            const int kb  = (off + l * 16) & 63;
            async16(smem + off,        (const char*)(W   + (size_t)(g0 + row) * 256 + k0) + kb);
            async16(smem + 8192 + off, (const char*)(hin + (size_t)(n0 + row) * 256 + k0) + kb);
        }
        __syncthreads();
        bf16x8 af[4], bfv[4];
        #pragma unroll
        for (int mf = 0; mf < 4; ++mf)
            af[mf] = *(const bf16x8*)(smem + ((wm * 64 + mf * 16 + lrow) * 64 + lkb));
        #pragma unroll
        for (int nf = 0; nf < 4; ++nf)
            bfv[nf] = *(const bf16x8*)(smem + 8192 + ((wn * 64 + nf * 16 + lrow) * 64 + lkb));
        #pragma unroll
        for (int mf = 0; mf < 4; ++mf)
            #pragma unroll
            for (int nf = 0; nf < 4; ++nf)
                acc[mf][nf] = __builtin_amdgcn_mfma_f32_16x16x32_bf16(af[mf], bfv[nf], acc[mf][nf], 0, 0, 0);
        __syncthreads();
    }

    // epilogue: cell update (lane-local gates) + LDS transpose for h store
    float* T = ((float*)smem) + w * 1024;     // 16 j x 64 n per wave
    const int jb = (g0 >> 2) + wm * 16;
    const int nb = n0 + wn * 64;
    #pragma unroll
    for (int nf = 0; nf < 4; ++nf) {
        const int n = nb + nf * 16 + lrow;
        const int len = seg_lens[n];
        const bool valid = pos < len;
        const float* pr = proj + (valid ? tokens[n * 16 + pos] : 0) * 1024;
        #pragma unroll
        for (int mf = 0; mf < 4; ++mf) {
            const int j = jb + mf * 4 + (l >> 4);
            float4 pv = *(const float4*)(pr + 4 * j);
            float hv = 0.f;
            if (valid) {
                float gi_ = acc[mf][nf][0] + pv.x;
                float gf_ = acc[mf][nf][1] + pv.y;
                float gg_ = acc[mf][nf][2] + pv.z;
                float go_ = acc[mf][nf][3] + pv.w;
                size_t ci = (size_t)j * 16384 + n;
                float cold = c[ci];
                float cn = sigm(gf_) * cold + sigm(gi_) * tanhf(gg_);
                hv = sigm(go_) * tanhf(cn);
                c[ci] = cn;
            }
            T[(mf * 4 + (l >> 4)) * 64 + nf * 16 + lrow] = hv;
        }
    }
    __syncthreads();
    {
        const int n = nb + l;
        const int len = seg_lens[n];
        if (pos < len) {
            unsigned pk[8];
            #pragma unroll
            for (int i2 = 0; i2 < 8; ++i2) {
                float v0 = T[(2 * i2 + 0) * 64 + l];
                float v1 = T[(2 * i2 + 1) * 64 + l];
                pk[i2] = (unsigned)f2bf(v0) | ((unsigned)f2bf(v1) << 16);
            }
            uint4* dst = (uint4*)(hout + (size_t)n * 256 + jb);
            dst[0] = make_uint4(pk[0], pk[1], pk[2], pk[3]);
            dst[1] = make_uint4(pk[4], pk[5], pk[6], pk[7]);
        }
    }
}

// ---------------------------------------------------------------------------
// Build x[n'][576] bf16, n' = t*256+b: [h_f(parity) | h_b | lab_emb[prev]]
// ---------------------------------------------------------------------------
__global__ __launch_bounds__(256) void build_x(
    const unsigned short* __restrict__ fb0, const unsigned short* __restrict__ fb1,
    const unsigned short* __restrict__ bb0,
    const float* __restrict__ lab_emb, const int* __restrict__ labels,
    const int* __restrict__ seg_lens, unsigned short* __restrict__ x)
{
    const int np = blockIdx.x * 4 + (threadIdx.x >> 6);
    const int l = threadIdx.x & 63;
    const int t = np >> 8, b = np & 255;
    const int n = b * 64 + t;
    const unsigned short* hf = (seg_lens[n] & 1) ? fb1 : fb0;
    const unsigned* src_f = (const unsigned*)(hf + (size_t)n * 256);
    const unsigned* src_b = (const unsigned*)(bb0 + (size_t)n * 256);
    unsigned* dst = (unsigned*)(x + (size_t)np * 576);
    #pragma unroll
    for (int cc = 0; cc < 5; ++cc) {
        int wd = l + cc * 64;
        if (wd < 128) dst[wd] = src_f[wd];
        else if (wd < 256) dst[wd] = src_b[wd - 128];
        else if (wd < 288) {
            int e = (wd - 256) * 2;
            int prev = (t == 0) ? NLc : labels[n - 1];
            float2 lv = *(const float2*)&lab_emb[prev * 64 + e];
            dst[wd] = (unsigned)f2bf(lv.x) | ((unsigned)f2bf(lv.y) << 16);
        }
    }
}

// ---------------------------------------------------------------------------
// gi GEMM (one 32-t chunk): giC[3j+q][np] = sum_k Wgi[3j+q][k]*x[np][k] + gbihP
// M=1536, N=8192, K=576. x is pre-offset to the chunk's first row.
// ---------------------------------------------------------------------------
__global__ __launch_bounds__(256) void gi_gemm(
    const unsigned short* __restrict__ Wgi, const unsigned short* __restrict__ x,
    const float* __restrict__ gbihP, float* __restrict__ giC)
{
    __shared__ __align__(16) char smem[16384];
    const int n0 = blockIdx.x * 128;
    const int g0 = blockIdx.y * 128;
    const int tid = threadIdx.x;
    const int w = tid >> 6, l = tid & 63;
    const int wm = w & 1, wn = w >> 1;
    const int lrow = l & 15, lkb = (l >> 4) * 16;

    f32x4 acc[4][4];
    #pragma unroll
    for (int mf = 0; mf < 4; ++mf)
        #pragma unroll
        for (int nf = 0; nf < 4; ++nf)
            acc[mf][nf] = (f32x4){0.f, 0.f, 0.f, 0.f};

    for (int it = 0; it < 18; ++it) {
        const int k0 = it * 32;
        #pragma unroll
        for (int rr = 0; rr < 2; ++rr) {
            const int off = (rr * 4 + w) * 1024;
            const int row = (off + l * 16) >> 6;
            const int kb  = (off + l * 16) & 63;
            async16(smem + off,        (const char*)(Wgi + (size_t)(g0 + row) * 576 + k0) + kb);
            async16(smem + 8192 + off, (const char*)(x   + (size_t)(n0 + row) * 576 + k0) + kb);
        }
        __syncthreads();
        bf16x8 af[4], bfv[4];
        #pragma unroll
        for (int mf = 0; mf < 4; ++mf)
            af[mf] = *(const bf16x8*)(smem + ((wm * 64 + mf * 16 + lrow) * 64 + lkb));
        #pragma unroll
        for (int nf = 0; nf < 4; ++nf)
            bfv[nf] = *(const bf16x8*)(smem + 8192 + ((wn * 64 + nf * 16 + lrow) * 64 + lkb));
        #pragma unroll
        for (int mf = 0; mf < 4; ++mf)
            #pragma unroll
            for (int nf = 0; nf < 4; ++nf)
                acc[mf][nf] = __builtin_amdgcn_mfma_f32_16x16x32_bf16(af[mf], bfv[nf], acc[mf][nf], 0, 0, 0);
        __syncthreads();
    }
    #pragma unroll
    for (int mf = 0; mf < 4; ++mf) {
        const int rbase = g0 + wm * 64 + mf * 16 + (l >> 4) * 4;
        const float* bq = gbihP + rbase;
        #pragma unroll
        for (int nf = 0; nf < 4; ++nf) {
            const int np = n0 + wn * 64 + nf * 16 + lrow;
            #pragma unroll
            for (int reg = 0; reg < 4; ++reg)
                giC[(size_t)(rbase + reg) * 8192 + np] = acc[mf][nf][reg] + bq[reg];
        }
    }
}

// ---------------------------------------------------------------------------
// GRU step: gh^T[4j+q][b] = sum_k Wg[4j+q][k]*hbf_in[b][k]; fused cell.
// M=2048 (q=3 pad), N=256, K=512. h f32 in hsT[t] [j][b]; bf16 ping-pong hbf.
// giC is the current 32-t chunk; column = (t&31)*256 + b, row stride 8192.
// ---------------------------------------------------------------------------
__global__ __launch_bounds__(256) void gru_step(
    const unsigned short* __restrict__ Wg, const float* __restrict__ giC,
    const float* __restrict__ gbhhP,
    const unsigned short* __restrict__ hbf_in, unsigned short* __restrict__ hbf_out,
    const float* __restrict__ hsT_prev, float* __restrict__ hsT_out, int t)
{
    __shared__ __align__(16) char smem[16384];
    const int b0 = blockIdx.x * 128;
    const int g0 = blockIdx.y * 128;
    const int tid = threadIdx.x;
    const int w = tid >> 6, l = tid & 63;
    const int wm = w & 1, wn = w >> 1;
    const int lrow = l & 15, lkb = (l >> 4) * 16;

    f32x4 acc[4][4];
    #pragma unroll
    for (int mf = 0; mf < 4; ++mf)
        #pragma unroll
        for (int nf = 0; nf < 4; ++nf)
            acc[mf][nf] = (f32x4){0.f, 0.f, 0.f, 0.f};

    for (int it = 0; it < 16; ++it) {
        const int k0 = it * 32;
        #pragma unroll
        for (int rr = 0; rr < 2; ++rr) {
            const int off = (rr * 4 + w) * 1024;
            const int row = (off + l * 16) >> 6;
            const int kb  = (off + l * 16) & 63;
            async16(smem + off,        (const char*)(Wg     + (size_t)(g0 + row) * 512 + k0) + kb);
            async16(smem + 8192 + off, (const char*)(hbf_in + (size_t)(b0 + row) * 512 + k0) + kb);
        }
        __syncthreads();
        bf16x8 af[4], bfv[4];
        #pragma unroll
        for (int mf = 0; mf < 4; ++mf)
            af[mf] = *(const bf16x8*)(smem + ((wm * 64 + mf * 16 + lrow) * 64 + lkb));
        #pragma unroll
        for (int nf = 0; nf < 4; ++nf)
            bfv[nf] = *(const bf16x8*)(smem + 8192 + ((wn * 64 + nf * 16 + lrow) * 64 + lkb));
        #pragma unroll
        for (int mf = 0; mf < 4; ++mf)
            #pragma unroll
            for (int nf = 0; nf < 4; ++nf)
                acc[mf][nf] = __builtin_amdgcn_mfma_f32_16x16x32_bf16(af[mf], bfv[nf], acc[mf][nf], 0, 0, 0);
        __syncthreads();
    }

    float* T = ((float*)smem) + w * 1024;
    const int jb = (g0 >> 2) + wm * 16;
    const int bb2 = b0 + wn * 64;
    #pragma unroll
    for (int nf = 0; nf < 4; ++nf) {
        const int b = bb2 + nf * 16 + lrow;
        const int col = (t & 31) * 256 + b;
        #pragma unroll
        for (int mf = 0; mf < 4; ++mf) {
            const int j = jb + mf * 4 + (l >> 4);
            float4 bq = *(const float4*)(gbhhP + 4 * j);
            float ghr = acc[mf][nf][0] + bq.x;
            float ghz = acc[mf][nf][1] + bq.y;
            float ghn = acc[mf][nf][2] + bq.z;
            float gir = giC[(size_t)(3 * j + 0) * 8192 + col];
            float giz = giC[(size_t)(3 * j + 1) * 8192 + col];
            float gin = giC[(size_t)(3 * j + 2) * 8192 + col];
            float r = sigm(gir + ghr);
            float z = sigm(giz + ghz);
            float ng = tanhf(gin + r * ghn);
            float hp = hsT_prev[j * 256 + b];
            float hn = (1.f - z) * ng + z * hp;
            hsT_out[j * 256 + b] = hn;
            T[(mf * 4 + (l >> 4)) * 64 + nf * 16 + lrow] = hn;
        }
    }
    __syncthreads();
    {
        const int b = bb2 + l;
        unsigned pk[8];
        #pragma unroll
        for (int i2 = 0; i2 < 8; ++i2) {
            float v0 = T[(2 * i2 + 0) * 64 + l];
            float v1 = T[(2 * i2 + 1) * 64 + l];
            pk[i2] = (unsigned)f2bf(v0) | ((unsigned)f2bf(v1) << 16);
        }
        uint4* dst = (uint4*)(hbf_out + (size_t)b * 512 + jb);
        dst[0] = make_uint4(pk[0], pk[1], pk[2], pk[3]);
        dst[1] = make_uint4(pk[4], pk[5], pk[6], pk[7]);
    }
}

// ---------------------------------------------------------------------------
// logits[b][t][l] = sum_j hsT[t+1][j][b] * Wout[l][j] + bout[l]
// ---------------------------------------------------------------------------
__global__ __launch_bounds__(256) void logits_k(
    const float* __restrict__ hsT, const float* __restrict__ Wout,
    const float* __restrict__ bout, float* __restrict__ out)
{
    const int t = blockIdx.x;
    const int b = threadIdx.x;
    const float* h = hsT + (size_t)(t + 1) * 131072;
    float acc[17];
    #pragma unroll
    for (int l2 = 0; l2 < 17; ++l2) acc[l2] = bout[l2];
    for (int j = 0; j < 512; ++j) {
        float hv = h[j * 256 + b];
        #pragma unroll
        for (int l2 = 0; l2 < 17; ++l2) acc[l2] += hv * Wout[l2 * 512 + j];
    }
    float* o = out + ((size_t)b * 64 + t) * 17;
    #pragma unroll
    for (int l2 = 0; l2 < 17; ++l2) o[l2] = acc[l2];
}

} // namespace

extern "C" void kernel_launch(void* const* d_in, const int* in_sizes, int n_in,
                              void* d_out, int out_size, void* d_ws, size_t ws_size,
                              hipStream_t stream)
{
    const int*   tokens   = (const int*)d_in[0];
    const int*   seg_lens = (const int*)d_in[1];
    const int*   labels   = (const int*)d_in[2];
    const float* seg_emb  = (const float*)d_in[3];
    const float* Wih_f    = (const float*)d_in[4];
    const float* Whh_f    = (const float*)d_in[5];
    const float* bih_f    = (const float*)d_in[6];
    const float* bhh_f    = (const float*)d_in[7];
    const float* Wih_b    = (const float*)d_in[8];
    const float* Whh_b    = (const float*)d_in[9];
    const float* bih_b    = (const float*)d_in[10];
    const float* bhh_b    = (const float*)d_in[11];
    const float* lab_emb  = (const float*)d_in[12];
    const float* gWih     = (const float*)d_in[13];
    const float* gWhh     = (const float*)d_in[14];
    const float* gbih     = (const float*)d_in[15];
    const float* gbhh     = (const float*)d_in[16];
    const float* Wout     = (const float*)d_in[17];
    const float* bout     = (const float*)d_in[18];
    float* out = (float*)d_out;

    // Workspace (~120 MiB, < 128.5 MiB proven available by round 1).
    // R (64 MiB) time-shared: [fb0|fb1|bb0|bb1|cT] during LSTM/build_x,
    // then giC (48 MiB, one 32-t GRU input-gate chunk, recomputed at t=32).
    char* p = (char*)d_ws;
    auto take = [&](size_t bytes) { char* r = p; p += (bytes + 255) & ~size_t(255); return r; };
    unsigned short* Wl   = (unsigned short*)take((size_t)2 * 1024 * 256 * 2);
    float*          projP= (float*)take((size_t)2 * 3 * 1024 * 4);
    unsigned short* Wg   = (unsigned short*)take((size_t)2048 * 512 * 2);
    float*          gbhhP= (float*)take((size_t)2048 * 4);
    unsigned short* Wgi  = (unsigned short*)take((size_t)1536 * 576 * 2);
    float*          gbihP= (float*)take((size_t)1536 * 4);
    unsigned short* hbf  = (unsigned short*)take((size_t)2 * 256 * 512 * 2);
    unsigned short* xbuf = (unsigned short*)take((size_t)16384 * 576 * 2);   // 18 MiB
    float*          hsT  = (float*)take((size_t)65 * 512 * 256 * 4);         // 32.5 MiB
    char*           R    = take((size_t)64 << 20);                           // 64 MiB

    unsigned short* fb[2] = {(unsigned short*)R, (unsigned short*)(R + 8388608)};
    unsigned short* bb[2] = {(unsigned short*)(R + 16777216), (unsigned short*)(R + 25165824)};
    float* cT  = (float*)(R + 33554432);        // 2 dirs x 16 MiB -> ends at 64 MiB
    float* giC = (float*)R;                     // 1536 x 8192 f32 = 48 MiB

    hipMemsetAsync(R, 0, (size_t)64 << 20, stream);               // fb,bb,cT
    hipMemsetAsync(hbf, 0, (size_t)2 * 256 * 512 * 2, stream);    // GRU bf16 state
    hipMemsetAsync(hsT, 0, (size_t)512 * 256 * 4, stream);        // GRU h_{-1}=0

    prep_lstm<<<8, 256, 0, stream>>>(Whh_f, Whh_b, Wih_f, bih_f, bhh_f,
                                     Wih_b, bih_b, bhh_b, seg_emb, Wl, projP);
    prep_gru<<<14, 256, 0, stream>>>(gWhh, gbhh, gWih, gbih, Wg, gbhhP, Wgi, gbihP);

    for (int s = 0; s < 16; ++s) {
        lstm_step<<<dim3(128, 8, 2), 256, 0, stream>>>(
            Wl, projP, tokens, seg_lens,
            fb[s & 1], fb[(s + 1) & 1], bb[s & 1], bb[(s + 1) & 1], cT, s);
    }

    build_x<<<4096, 256, 0, stream>>>(fb[0], fb[1], bb[0], lab_emb, labels, seg_lens, xbuf);

    for (int half = 0; half < 2; ++half) {
        // giC chunk for t in [half*32, half*32+32): overwrites fb/bb/cT (dead)
        gi_gemm<<<dim3(64, 12), 256, 0, stream>>>(
            Wgi, xbuf + (size_t)half * 8192 * 576, gbihP, giC);
        for (int t = half * 32; t < half * 32 + 32; ++t) {
            gru_step<<<dim3(2, 16), 256, 0, stream>>>(
                Wg, giC, gbhhP,
                hbf + (size_t)(t & 1) * 131072, hbf + (size_t)((t + 1) & 1) * 131072,
                hsT + (size_t)t * 131072, hsT + (size_t)(t + 1) * 131072, t);
        }
    }

    logits_k<<<64, 256, 0, stream>>>(hsT, Wout, bout, out);
}